// Round 3
// baseline (349.696 us; speedup 1.0000x reference)
//
#include <hip/hip_runtime.h>
#include <cstdint>
#include <cstddef>

typedef __attribute__((ext_vector_type(8))) short short8;   // 8 bf16 (4 VGPRs)
typedef __attribute__((ext_vector_type(4))) float f32x4;    // 4 fp32 acc

#define NN 4096
#define HH 512
#define EE 65536

// async global->LDS, 16B per lane (dest must be linear: base + lane*16)
#define GLOAD(gp, lp) __builtin_amdgcn_global_load_lds( \
    (const __attribute__((address_space(1))) void*)(gp), \
    (__attribute__((address_space(3))) void*)(lp), 16, 0, 0)

__device__ __forceinline__ unsigned short f2bf(float x) {
    union { float f; unsigned u; } un; un.f = x;
    unsigned r = un.u + 0x7fffu + ((un.u >> 16) & 1u);   // round-to-nearest-even
    return (unsigned short)(r >> 16);
}

// ---------------- edge counting sort (deterministic aggregation order) ----------------
__global__ void k_hist(const int* __restrict__ dst, int* __restrict__ cnt) {
    int e = blockIdx.x * 256 + threadIdx.x;
    if (e < EE) atomicAdd(&cnt[dst[e]], 1);
}

__global__ void k_scan(const int* __restrict__ cnt, int* __restrict__ starts) {
    __shared__ int sub[256];
    __shared__ int suboff[256];
    int t = threadIdx.x;
    int c[16]; int s = 0; int base = t * 16;
    for (int i = 0; i < 16; ++i) { c[i] = cnt[base + i]; s += c[i]; }
    sub[t] = s;
    __syncthreads();
    if (t == 0) { int acc = 0; for (int i = 0; i < 256; ++i) { suboff[i] = acc; acc += sub[i]; } }
    __syncthreads();
    int run = suboff[t];
    for (int i = 0; i < 16; ++i) { starts[base + i] = run; run += c[i]; }
    if (t == 255) starts[NN] = run;
}

__global__ void k_scatter(const int* __restrict__ src, const int* __restrict__ dst,
                          const int* __restrict__ starts, int* __restrict__ cursor,
                          int* __restrict__ sorted) {
    int e = blockIdx.x * 256 + threadIdx.x;
    if (e < EE) {
        int d = dst[e];
        int p = starts[d] + atomicAdd(&cursor[d], 1);
        sorted[p] = src[e];
    }
}

__global__ void k_binsort(const int* __restrict__ starts, int* __restrict__ a) {
    int d = blockIdx.x * 256 + threadIdx.x;
    if (d < NN) {
        int s = starts[d], e = starts[d + 1];
        for (int i = s + 1; i < e; ++i) {
            int v = a[i]; int j = i - 1;
            while (j >= s && a[j] > v) { a[j + 1] = a[j]; --j; }
            a[j + 1] = v;
        }
    }
}

// ---------------- fused: feat f32 -> bf16 convert + feat . Wp0 partial dot ----------------
// Exactly 8 grid-stride steps (4M float4 / 524288 threads); unrolled 2x4 for ILP.
__global__ __launch_bounds__(256) void k_cvtdot0(const float* __restrict__ feat,
                                                 const float* __restrict__ w,
                                                 unsigned short* __restrict__ featb,
                                                 float* __restrict__ part) {
    const long S = 2048L * 256L;
    const long i0 = blockIdx.x * 256L + threadIdx.x;
    float a0 = 0.f, a1 = 0.f;
#pragma unroll
    for (int u = 0; u < 2; ++u) {
        const long b = i0 + (long)u * 4 * S;
        float4 v[4], wA[4], wB[4];
#pragma unroll
        for (int k = 0; k < 4; ++k) {
            const long idx = b + (long)k * S;
            v[k]  = ((const float4*)feat)[idx];
            wA[k] = ((const float4*)w)[2 * idx];
            wB[k] = ((const float4*)w)[2 * idx + 1];
        }
#pragma unroll
        for (int k = 0; k < 4; ++k) {
            const long idx = b + (long)k * S;
            ushort4 o;
            o.x = f2bf(v[k].x); o.y = f2bf(v[k].y); o.z = f2bf(v[k].z); o.w = f2bf(v[k].w);
            ((ushort4*)featb)[idx] = o;
            a0 += v[k].x * wA[k].x + v[k].y * wA[k].z + v[k].z * wB[k].x + v[k].w * wB[k].z;
            a1 += v[k].x * wA[k].y + v[k].y * wA[k].w + v[k].z * wB[k].y + v[k].w * wB[k].w;
        }
    }
    __shared__ float s0[256], s1[256];
    int t = threadIdx.x;
    s0[t] = a0; s1[t] = a1;
    __syncthreads();
    for (int s = 128; s > 0; s >>= 1) {
        if (t < s) { s0[t] += s0[t + s]; s1[t] += s1[t + s]; }
        __syncthreads();
    }
    if (t == 0) { part[2 * blockIdx.x] = s0[0]; part[2 * blockIdx.x + 1] = s1[0]; }
}

// W [K][N] f32  ->  Wt [N][K] bf16   (single large weight)
__global__ __launch_bounds__(256) void k_transcvt(const float* __restrict__ W,
                                                  unsigned short* __restrict__ Wt, int K, int N) {
    __shared__ float tile[32][33];
    const int k0 = blockIdx.x * 32, n0 = blockIdx.y * 32;
    const int tx = threadIdx.x & 31, ty = threadIdx.x >> 5;
    for (int r = ty; r < 32; r += 8)
        tile[r][tx] = W[(size_t)(k0 + r) * N + n0 + tx];
    __syncthreads();
    for (int r = ty; r < 32; r += 8)
        Wt[(size_t)(n0 + r) * K + k0 + tx] = f2bf(tile[tx][r]);
}

// batched 512x512 transposes: z=0 -> W0b, z=1..3 -> WRa[z-1], z=4..6 -> WRb[z-4]
__global__ __launch_bounds__(256) void k_transcvt7(const float* __restrict__ W0b,
                                                   const float* __restrict__ WRa,
                                                   const float* __restrict__ WRb,
                                                   unsigned short* __restrict__ wt) {
    __shared__ float tile[32][33];
    const int z = blockIdx.z;
    const float* W = (z == 0) ? W0b
                   : (z < 4) ? WRa + (size_t)(z - 1) * HH * HH
                             : WRb + (size_t)(z - 4) * HH * HH;
    unsigned short* Wt = wt + (size_t)z * HH * HH;
    const int k0 = blockIdx.x * 32, n0 = blockIdx.y * 32;
    const int tx = threadIdx.x & 31, ty = threadIdx.x >> 5;
    for (int r = ty; r < 32; r += 8)
        tile[r][tx] = W[(size_t)(k0 + r) * HH + n0 + tx];
    __syncthreads();
    for (int r = ty; r < 32; r += 8)
        Wt[(size_t)(n0 + r) * HH + k0 + tx] = f2bf(tile[tx][r]);
}

// ---------------- bf16 MFMA GEMM: C = A[M][K] @ Bt[N][K]^T ----------------
// Tile 128 x BN, BK=32, double-buffered LDS via global_load_lds, split-K = gridDim.z.
// EPI 0: store raw f32 partial (offset z*M*N). EPI 1: +bias,BN,ReLU -> bf16.
// EPI 2: +bias,BN,ReLU,BN,ReLU -> f32. DOT: also accumulate out . wq[:,0:2] per block.
template<int EPI, int BN, bool DOT>
__global__ __launch_bounds__(256) void k_gemm(
    const unsigned short* __restrict__ A, const unsigned short* __restrict__ Bt,
    int M, int N, int K,
    const float* __restrict__ bias,
    const float* __restrict__ g1p, const float* __restrict__ b1p,
    const float* __restrict__ m1p, const float* __restrict__ v1p,
    const float* __restrict__ g2p, const float* __restrict__ b2p,
    const float* __restrict__ m2p, const float* __restrict__ v2p,
    float* __restrict__ outf, unsigned short* __restrict__ outb,
    const float* __restrict__ wq, float* __restrict__ part, int slotbase)
{
    __shared__ alignas(16) unsigned short As[2][128 * 32];
    __shared__ alignas(16) unsigned short Bs[2][BN * 32];
    const int t = threadIdx.x;
    const int lane = t & 63, w = t >> 6;
    const int wr = w >> 1, wc = w & 1;
    const int l15 = lane & 15, l4 = lane >> 4;
    const int m0 = blockIdx.x * 128, n0 = blockIdx.y * BN;
    constexpr int NJ = BN / 32;          // 16-col frags per wave in N
    constexpr int WCW = BN / 2;          // wave column width

    f32x4 acc[4][NJ];
#pragma unroll
    for (int i = 0; i < 4; ++i)
#pragma unroll
        for (int j = 0; j < NJ; ++j) acc[i][j] = (f32x4){0.f, 0.f, 0.f, 0.f};

    const int Kc = K / gridDim.z;
    const int kbase = blockIdx.z * Kc;
    const unsigned short* Ab = A + (size_t)m0 * K + kbase;
    const unsigned short* Bb = Bt + (size_t)n0 * K + kbase;
    const unsigned short* ga0 = Ab + (size_t)(t >> 2) * K + (t & 3) * 8;
    const unsigned short* ga1 = ga0 + (size_t)64 * K;
    const unsigned short* gb0 = Bb + (size_t)(t >> 2) * K + (t & 3) * 8;
    const unsigned short* gb1 = gb0 + (size_t)64 * K;

    auto stage = [&](int kt, int buf) {
        const int ko = kt * 32;
        GLOAD(ga0 + ko, &As[buf][t * 8]);
        GLOAD(ga1 + ko, &As[buf][(t + 256) * 8]);
        GLOAD(gb0 + ko, &Bs[buf][t * 8]);
        if constexpr (BN == 128) {
            GLOAD(gb1 + ko, &Bs[buf][(t + 256) * 8]);
        }
    };

    const int nk = Kc >> 5;
    stage(0, 0);
    __syncthreads();                     // drains vmcnt: buf0 ready
    for (int kt = 0; kt < nk; ++kt) {
        const int cur = kt & 1;
        if (kt + 1 < nk) stage(kt + 1, cur ^ 1);
        short8 aF[4], bF[NJ];
#pragma unroll
        for (int i = 0; i < 4; ++i)
            aF[i] = *(const short8*)(&As[cur][(wr * 64 + i * 16 + l15) * 32 + 8 * l4]);
#pragma unroll
        for (int j = 0; j < NJ; ++j)
            bF[j] = *(const short8*)(&Bs[cur][(wc * WCW + j * 16 + l15) * 32 + 8 * l4]);
#pragma unroll
        for (int i = 0; i < 4; ++i)
#pragma unroll
            for (int j = 0; j < NJ; ++j)
                acc[i][j] = __builtin_amdgcn_mfma_f32_16x16x32_bf16(aF[i], bF[j], acc[i][j], 0, 0, 0);
        __syncthreads();                 // next buffer ready, all reads done
    }

    const int mrow = m0 + wr * 64;
    float* op = outf + (EPI == 0 ? (size_t)blockIdx.z * M * N : 0);
    float d0 = 0.f, d1 = 0.f;
#pragma unroll
    for (int j = 0; j < NJ; ++j) {
        const int cg = n0 + wc * WCW + j * 16 + l15;
        float bi = 0.f, sc1 = 1.f, sh1 = 0.f, sc2 = 1.f, sh2 = 0.f;
        if (EPI >= 1) {
            bi = bias[cg];
            sc1 = rsqrtf(v1p[cg] + 1e-5f) * g1p[cg];
            sh1 = b1p[cg] - m1p[cg] * sc1;
        }
        if (EPI == 2) {
            sc2 = rsqrtf(v2p[cg] + 1e-5f) * g2p[cg];
            sh2 = b2p[cg] - m2p[cg] * sc2;
        }
#pragma unroll
        for (int i = 0; i < 4; ++i) {
#pragma unroll
            for (int r = 0; r < 4; ++r) {
                const int rg = mrow + i * 16 + l4 * 4 + r;
                float x = acc[i][j][r];
                if (EPI == 0) {
                    op[(size_t)rg * N + cg] = x;
                } else if (EPI == 1) {
                    x = fmaxf((x + bi) * sc1 + sh1, 0.f);
                    outb[(size_t)rg * N + cg] = f2bf(x);
                } else {
                    x = fmaxf((x + bi) * sc1 + sh1, 0.f);
                    x = fmaxf(x * sc2 + sh2, 0.f);
                    op[(size_t)rg * N + cg] = x;
                    if constexpr (DOT) {
                        float2 wv = ((const float2*)wq)[(size_t)rg * N + cg];
                        d0 += x * wv.x; d1 += x * wv.y;
                    }
                }
            }
        }
    }
    if constexpr (DOT) {
        __shared__ float r0[256], r1[256];
        r0[t] = d0; r1[t] = d1;
        __syncthreads();
        for (int s = 128; s > 0; s >>= 1) {
            if (t < s) { r0[t] += r0[t + s]; r1[t] += r1[t + s]; }
            __syncthreads();
        }
        if (t == 0) {
            const int slot = slotbase + blockIdx.y * gridDim.x + blockIdx.x;
            part[2 * slot] = r0[0]; part[2 * slot + 1] = r1[0];
        }
    }
}

// sum 4 split-K partials -> G0
__global__ __launch_bounds__(256) void k_red4(const float* __restrict__ p, float* __restrict__ G0) {
    const long S = (long)NN * HH / 4;
    long i = blockIdx.x * 256L + threadIdx.x;
    float4 a = ((const float4*)p)[i];
    float4 b = ((const float4*)p)[i + S];
    float4 c = ((const float4*)p)[i + 2 * S];
    float4 d = ((const float4*)p)[i + 3 * S];
    float4 o;
    o.x = (a.x + b.x) + (c.x + d.x);
    o.y = (a.y + b.y) + (c.y + d.y);
    o.z = (a.z + b.z) + (c.z + d.z);
    o.w = (a.w + b.w) + (c.w + d.w);
    ((float4*)G0)[i] = o;
}

// ---------------- edge aggregation (gather-sum over sorted in-edges, 4x prefetch) ----------------
__global__ __launch_bounds__(128) void k_agg0(
    const float* __restrict__ G0, const int* __restrict__ starts, const int* __restrict__ sorted,
    const float* __restrict__ epsp, const float* __restrict__ bias,
    const float* __restrict__ bg, const float* __restrict__ bb,
    const float* __restrict__ bm, const float* __restrict__ bv,
    unsigned short* __restrict__ outb)
{
    const int d = blockIdx.x, t = threadIdx.x;
    const float ep = 1.0f + epsp[0];
    float4 own = ((const float4*)(G0 + (size_t)d * HH))[t];
    float sx = 0.f, sy = 0.f, sz = 0.f, sw = 0.f;
    const int e0 = starts[d], e1 = starts[d + 1];
    int i = e0;
    for (; i + 4 <= e1; i += 4) {
        int q0 = sorted[i], q1 = sorted[i + 1], q2 = sorted[i + 2], q3 = sorted[i + 3];
        float4 x0 = ((const float4*)(G0 + (size_t)q0 * HH))[t];
        float4 x1 = ((const float4*)(G0 + (size_t)q1 * HH))[t];
        float4 x2 = ((const float4*)(G0 + (size_t)q2 * HH))[t];
        float4 x3 = ((const float4*)(G0 + (size_t)q3 * HH))[t];
        sx += (x0.x + x1.x) + (x2.x + x3.x);
        sy += (x0.y + x1.y) + (x2.y + x3.y);
        sz += (x0.z + x1.z) + (x2.z + x3.z);
        sw += (x0.w + x1.w) + (x2.w + x3.w);
    }
    for (; i < e1; ++i) {
        float4 x = ((const float4*)(G0 + (size_t)sorted[i] * HH))[t];
        sx += x.x; sy += x.y; sz += x.z; sw += x.w;
    }
    float4 bi = ((const float4*)bias)[t];
    float4 g4 = ((const float4*)bg)[t];
    float4 b4 = ((const float4*)bb)[t];
    float4 m4 = ((const float4*)bm)[t];
    float4 v4 = ((const float4*)bv)[t];
    float x0 = ep * own.x + sx + bi.x;
    float x1 = ep * own.y + sy + bi.y;
    float x2 = ep * own.z + sz + bi.z;
    float x3 = ep * own.w + sw + bi.w;
    x0 = fmaxf((x0 - m4.x) * rsqrtf(v4.x + 1e-5f) * g4.x + b4.x, 0.f);
    x1 = fmaxf((x1 - m4.y) * rsqrtf(v4.y + 1e-5f) * g4.y + b4.y, 0.f);
    x2 = fmaxf((x2 - m4.z) * rsqrtf(v4.z + 1e-5f) * g4.z + b4.z, 0.f);
    x3 = fmaxf((x3 - m4.w) * rsqrtf(v4.w + 1e-5f) * g4.w + b4.w, 0.f);
    ushort4 o; o.x = f2bf(x0); o.y = f2bf(x1); o.z = f2bf(x2); o.w = f2bf(x3);
    ((ushort4*)(outb + (size_t)d * HH))[t] = o;
}

__global__ __launch_bounds__(128) void k_aggL(
    const float* __restrict__ hsrc, const int* __restrict__ starts, const int* __restrict__ sorted,
    const float* __restrict__ epsp, unsigned short* __restrict__ outb)
{
    const int d = blockIdx.x, t = threadIdx.x;
    const float ep = 1.0f + epsp[0];
    float4 own = ((const float4*)(hsrc + (size_t)d * HH))[t];
    float sx = 0.f, sy = 0.f, sz = 0.f, sw = 0.f;
    const int e0 = starts[d], e1 = starts[d + 1];
    int i = e0;
    for (; i + 4 <= e1; i += 4) {
        int q0 = sorted[i], q1 = sorted[i + 1], q2 = sorted[i + 2], q3 = sorted[i + 3];
        float4 x0 = ((const float4*)(hsrc + (size_t)q0 * HH))[t];
        float4 x1 = ((const float4*)(hsrc + (size_t)q1 * HH))[t];
        float4 x2 = ((const float4*)(hsrc + (size_t)q2 * HH))[t];
        float4 x3 = ((const float4*)(hsrc + (size_t)q3 * HH))[t];
        sx += (x0.x + x1.x) + (x2.x + x3.x);
        sy += (x0.y + x1.y) + (x2.y + x3.y);
        sz += (x0.z + x1.z) + (x2.z + x3.z);
        sw += (x0.w + x1.w) + (x2.w + x3.w);
    }
    for (; i < e1; ++i) {
        float4 x = ((const float4*)(hsrc + (size_t)sorted[i] * HH))[t];
        sx += x.x; sy += x.y; sz += x.z; sw += x.w;
    }
    ushort4 o;
    o.x = f2bf(ep * own.x + sx);
    o.y = f2bf(ep * own.y + sy);
    o.z = f2bf(ep * own.z + sz);
    o.w = f2bf(ep * own.w + sw);
    ((ushort4*)(outb + (size_t)d * HH))[t] = o;
}

__global__ __launch_bounds__(256) void k_final(const float* __restrict__ part, int nslot,
                                               const float* __restrict__ bp0, const float* __restrict__ bpR,
                                               float* __restrict__ out) {
    __shared__ float s0[256], s1[256];
    int t = threadIdx.x;
    float a0 = 0.f, a1 = 0.f;
    for (int i = t; i < nslot; i += 256) { a0 += part[2 * i]; a1 += part[2 * i + 1]; }
    s0[t] = a0; s1[t] = a1;
    __syncthreads();
    for (int s = 128; s > 0; s >>= 1) {
        if (t < s) { s0[t] += s0[t + s]; s1[t] += s1[t + s]; }
        __syncthreads();
    }
    if (t == 0) {
        out[0] = s0[0] + bp0[0] + bpR[0] + bpR[2] + bpR[4] + bpR[6];
        out[1] = s1[0] + bp0[1] + bpR[1] + bpR[3] + bpR[5] + bpR[7];
    }
}

extern "C" void kernel_launch(void* const* d_in, const int* in_sizes, int n_in,
                              void* d_out, int out_size, void* d_ws, size_t ws_size,
                              hipStream_t stream)
{
    const float* feat = (const float*)d_in[0];
    const int*   esrc = (const int*)d_in[1];
    const int*   edst = (const int*)d_in[2];
    const float* eps0 = (const float*)d_in[3];
    const float* W0a  = (const float*)d_in[4];
    const float* b0a  = (const float*)d_in[5];
    const float* W0b  = (const float*)d_in[6];
    const float* b0b  = (const float*)d_in[7];
    const float* bn0a_g = (const float*)d_in[8];
    const float* bn0a_b = (const float*)d_in[9];
    const float* bn0a_m = (const float*)d_in[10];
    const float* bn0a_v = (const float*)d_in[11];
    const float* bnA0_g = (const float*)d_in[12];
    const float* bnA0_b = (const float*)d_in[13];
    const float* bnA0_m = (const float*)d_in[14];
    const float* bnA0_v = (const float*)d_in[15];
    const float* bnO0_g = (const float*)d_in[16];
    const float* bnO0_b = (const float*)d_in[17];
    const float* bnO0_m = (const float*)d_in[18];
    const float* bnO0_v = (const float*)d_in[19];
    const float* epsR = (const float*)d_in[20];
    const float* WRa  = (const float*)d_in[21];
    const float* bRa  = (const float*)d_in[22];
    const float* WRb  = (const float*)d_in[23];
    const float* bRb  = (const float*)d_in[24];
    const float* bnRa_g = (const float*)d_in[25];
    const float* bnRa_b = (const float*)d_in[26];
    const float* bnRa_m = (const float*)d_in[27];
    const float* bnRa_v = (const float*)d_in[28];
    const float* bnAR_g = (const float*)d_in[29];
    const float* bnAR_b = (const float*)d_in[30];
    const float* bnAR_m = (const float*)d_in[31];
    const float* bnAR_v = (const float*)d_in[32];
    const float* bnOR_g = (const float*)d_in[33];
    const float* bnOR_b = (const float*)d_in[34];
    const float* bnOR_m = (const float*)d_in[35];
    const float* bnOR_v = (const float*)d_in[36];
    const float* Wp0 = (const float*)d_in[37];
    const float* bp0 = (const float*)d_in[38];
    const float* WpR = (const float*)d_in[39];
    const float* bpR = (const float*)d_in[40];
    float* out = (float*)d_out;

    char* ws = (char*)d_ws;
    const size_t MB = 1024 * 1024;
    int*   cnt    = (int*)(ws + 0x00000);
    int*   starts = (int*)(ws + 0x10000);
    int*   cursor = (int*)(ws + 0x20000);
    int*   sorted = (int*)(ws + 0x30000);     // 256 KiB
    float* part   = (float*)(ws + 0x70000);   // 3072*2 f32
    unsigned short* featb = (unsigned short*)(ws + 1 * MB);    // [4096][4096] bf16, 32 MiB
    unsigned short* w0at  = (unsigned short*)(ws + 33 * MB);   // [512][4096] bf16, 4 MiB
    unsigned short* wt    = (unsigned short*)(ws + 37 * MB);   // 7 x [512][512] bf16
    float* G0 = (float*)(ws + 41 * MB);                        // [4096][512] f32
    unsigned short* xb = (unsigned short*)(ws + 49 * MB);      // [4096][512] bf16
    unsigned short* yb = (unsigned short*)(ws + 53 * MB);      // [4096][512] bf16
    float* h = (float*)(ws + 57 * MB);                         // 4 x [4096][512] f32
    float* pbuf = (float*)(ws + 57 * MB);                      // split-K partials alias h (dead before h0 write)

    // ---- edge sort ----
    hipMemsetAsync(ws, 0, 0x30000, stream);
    k_hist<<<EE / 256, 256, 0, stream>>>(edst, cnt);
    k_scan<<<1, 256, 0, stream>>>(cnt, starts);
    k_scatter<<<EE / 256, 256, 0, stream>>>(esrc, edst, starts, cursor, sorted);
    k_binsort<<<NN / 256, 256, 0, stream>>>(starts, sorted);

    // ---- precision prep (+ fused feat.Wp0 readout dot) ----
    k_cvtdot0<<<2048, 256, 0, stream>>>(feat, Wp0, featb, part);
    k_transcvt<<<dim3(NN / 32, HH / 32), 256, 0, stream>>>(W0a, w0at, NN, HH);
    k_transcvt7<<<dim3(HH / 32, HH / 32, 7), 256, 0, stream>>>(W0b, WRa, WRb, wt);

    // ---- layer 0 (reassociated: G0 = feat@W0a first, then aggregate) ----
    k_gemm<0, 128, false><<<dim3(32, 4, 4), 256, 0, stream>>>(featb, w0at, NN, HH, NN,
        nullptr, nullptr, nullptr, nullptr, nullptr, nullptr, nullptr, nullptr, nullptr,
        pbuf, nullptr, nullptr, nullptr, 0);
    k_red4<<<2048, 256, 0, stream>>>(pbuf, G0);
    k_agg0<<<NN, 128, 0, stream>>>(G0, starts, sorted, eps0, b0a,
                                   bn0a_g, bn0a_b, bn0a_m, bn0a_v, xb);
    k_gemm<2, 64, true><<<dim3(32, 8), 256, 0, stream>>>(xb, wt, NN, HH, HH,
        b0b, bnA0_g, bnA0_b, bnA0_m, bnA0_v, bnO0_g, bnO0_b, bnO0_m, bnO0_v,
        h, nullptr, WpR, part, 2048);

    // ---- layers 1..3 ----
    for (int i = 0; i < 3; ++i) {
        const float* hp = h + (size_t)i * NN * HH;
        float* hn = h + (size_t)(i + 1) * NN * HH;
        k_aggL<<<NN, 128, 0, stream>>>(hp, starts, sorted, epsR + i, xb);
        k_gemm<1, 64, false><<<dim3(32, 8), 256, 0, stream>>>(xb, wt + (size_t)(1 + i) * HH * HH, NN, HH, HH,
            bRa + (size_t)i * HH,
            bnRa_g + (size_t)i * HH, bnRa_b + (size_t)i * HH, bnRa_m + (size_t)i * HH, bnRa_v + (size_t)i * HH,
            nullptr, nullptr, nullptr, nullptr,
            nullptr, yb, nullptr, nullptr, 0);
        k_gemm<2, 64, true><<<dim3(32, 8), 256, 0, stream>>>(yb, wt + (size_t)(4 + i) * HH * HH, NN, HH, HH,
            bRb + (size_t)i * HH,
            bnAR_g + (size_t)i * HH, bnAR_b + (size_t)i * HH, bnAR_m + (size_t)i * HH, bnAR_v + (size_t)i * HH,
            bnOR_g + (size_t)i * HH, bnOR_b + (size_t)i * HH, bnOR_m + (size_t)i * HH, bnOR_v + (size_t)i * HH,
            hn, nullptr, WpR + (size_t)(i + 1) * NN * HH * 2, part, 2048 + (i + 1) * 256);
    }

    // ---- jumping-knowledge readout final reduce ----
    k_final<<<1, 256, 0, stream>>>(part, 2048 + 4 * 256, bp0, bpR, out);
}

// Round 4
// 315.201 us; speedup vs baseline: 1.1094x; 1.1094x over previous
//
#include <hip/hip_runtime.h>
#include <cstdint>
#include <cstddef>

typedef __attribute__((ext_vector_type(8))) short short8;   // 8 bf16 (4 VGPRs)
typedef __attribute__((ext_vector_type(4))) float f32x4;    // 4 fp32 acc
typedef __attribute__((ext_vector_type(4))) float f4;       // nontemporal-friendly float4
typedef __attribute__((ext_vector_type(4))) unsigned short us4;

#define NN 4096
#define HH 512
#define EE 65536

// async global->LDS, 16B per lane (dest must be linear: base + lane*16)
#define GLOAD(gp, lp) __builtin_amdgcn_global_load_lds( \
    (const __attribute__((address_space(1))) void*)(gp), \
    (__attribute__((address_space(3))) void*)(lp), 16, 0, 0)

__device__ __forceinline__ unsigned short f2bf(float x) {
    union { float f; unsigned u; } un; un.f = x;
    unsigned r = un.u + 0x7fffu + ((un.u >> 16) & 1u);   // round-to-nearest-even
    return (unsigned short)(r >> 16);
}
__device__ __forceinline__ float b2f(unsigned short v) {
    union { unsigned u; float f; } un; un.u = ((unsigned)v) << 16; return un.f;
}

// ---------------- edge counting sort (deterministic aggregation order) ----------------
__global__ void k_hist(const int* __restrict__ dst, int* __restrict__ cnt) {
    int e = blockIdx.x * 256 + threadIdx.x;
    if (e < EE) atomicAdd(&cnt[dst[e]], 1);
}

__global__ void k_scan(const int* __restrict__ cnt, int* __restrict__ starts) {
    __shared__ int sub[256];
    __shared__ int suboff[256];
    int t = threadIdx.x;
    int c[16]; int s = 0; int base = t * 16;
    for (int i = 0; i < 16; ++i) { c[i] = cnt[base + i]; s += c[i]; }
    sub[t] = s;
    __syncthreads();
    if (t == 0) { int acc = 0; for (int i = 0; i < 256; ++i) { suboff[i] = acc; acc += sub[i]; } }
    __syncthreads();
    int run = suboff[t];
    for (int i = 0; i < 16; ++i) { starts[base + i] = run; run += c[i]; }
    if (t == 255) starts[NN] = run;
}

__global__ void k_scatter(const int* __restrict__ src, const int* __restrict__ dst,
                          const int* __restrict__ starts, int* __restrict__ cursor,
                          int* __restrict__ sorted) {
    int e = blockIdx.x * 256 + threadIdx.x;
    if (e < EE) {
        int d = dst[e];
        int p = starts[d] + atomicAdd(&cursor[d], 1);
        sorted[p] = src[e];
    }
}

__global__ void k_binsort(const int* __restrict__ starts, int* __restrict__ a) {
    int d = blockIdx.x * 256 + threadIdx.x;
    if (d < NN) {
        int s = starts[d], e = starts[d + 1];
        for (int i = s + 1; i < e; ++i) {
            int v = a[i]; int j = i - 1;
            while (j >= s && a[j] > v) { a[j + 1] = a[j]; --j; }
            a[j + 1] = v;
        }
    }
}

// ---------------- fused: feat f32 -> bf16 convert + feat . Wp0 partial dot ----------------
// Block-contiguous: block b owns float4s [b*1024, (b+1)*1024); 4 lane-unit-stride
// sub-steps of 256. All 12 loads issued before use; nontemporal everywhere.
__global__ __launch_bounds__(256) void k_cvtdot0(const float* __restrict__ feat,
                                                 const float* __restrict__ w,
                                                 unsigned short* __restrict__ featb,
                                                 float* __restrict__ part) {
    const int t = threadIdx.x;
    const long B = (long)blockIdx.x * 1024 + t;     // float4 index
    const f4* ff = (const f4*)feat;
    const f4* ww = (const f4*)w;
    f4 v[4], wA[4], wB[4];
#pragma unroll
    for (int k = 0; k < 4; ++k)
        v[k] = __builtin_nontemporal_load(ff + B + k * 256);
#pragma unroll
    for (int k = 0; k < 4; ++k) {
        wA[k] = __builtin_nontemporal_load(ww + 2 * (B + k * 256));
        wB[k] = __builtin_nontemporal_load(ww + 2 * (B + k * 256) + 1);
    }
    float a0 = 0.f, a1 = 0.f;
#pragma unroll
    for (int k = 0; k < 4; ++k) {
        us4 o;
        o.x = f2bf(v[k].x); o.y = f2bf(v[k].y); o.z = f2bf(v[k].z); o.w = f2bf(v[k].w);
        __builtin_nontemporal_store(o, (us4*)featb + B + k * 256);
        a0 += v[k].x * wA[k].x + v[k].y * wA[k].z + v[k].z * wB[k].x + v[k].w * wB[k].z;
        a1 += v[k].x * wA[k].y + v[k].y * wA[k].w + v[k].z * wB[k].y + v[k].w * wB[k].w;
    }
    __shared__ float s0[256], s1[256];
    s0[t] = a0; s1[t] = a1;
    __syncthreads();
    for (int s = 128; s > 0; s >>= 1) {
        if (t < s) { s0[t] += s0[t + s]; s1[t] += s1[t + s]; }
        __syncthreads();
    }
    if (t == 0) { part[2 * blockIdx.x] = s0[0]; part[2 * blockIdx.x + 1] = s1[0]; }
}

// W [K][N] f32  ->  Wt [N][K] bf16   (single large weight)
__global__ __launch_bounds__(256) void k_transcvt(const float* __restrict__ W,
                                                  unsigned short* __restrict__ Wt, int K, int N) {
    __shared__ float tile[32][33];
    const int k0 = blockIdx.x * 32, n0 = blockIdx.y * 32;
    const int tx = threadIdx.x & 31, ty = threadIdx.x >> 5;
    for (int r = ty; r < 32; r += 8)
        tile[r][tx] = W[(size_t)(k0 + r) * N + n0 + tx];
    __syncthreads();
    for (int r = ty; r < 32; r += 8)
        Wt[(size_t)(n0 + r) * K + k0 + tx] = f2bf(tile[tx][r]);
}

// batched 512x512 transposes: z=0 -> W0b, z=1..3 -> WRa[z-1], z=4..6 -> WRb[z-4]
__global__ __launch_bounds__(256) void k_transcvt7(const float* __restrict__ W0b,
                                                   const float* __restrict__ WRa,
                                                   const float* __restrict__ WRb,
                                                   unsigned short* __restrict__ wt) {
    __shared__ float tile[32][33];
    const int z = blockIdx.z;
    const float* W = (z == 0) ? W0b
                   : (z < 4) ? WRa + (size_t)(z - 1) * HH * HH
                             : WRb + (size_t)(z - 4) * HH * HH;
    unsigned short* Wt = wt + (size_t)z * HH * HH;
    const int k0 = blockIdx.x * 32, n0 = blockIdx.y * 32;
    const int tx = threadIdx.x & 31, ty = threadIdx.x >> 5;
    for (int r = ty; r < 32; r += 8)
        tile[r][tx] = W[(size_t)(k0 + r) * HH + n0 + tx];
    __syncthreads();
    for (int r = ty; r < 32; r += 8)
        Wt[(size_t)(n0 + r) * HH + k0 + tx] = f2bf(tile[tx][r]);
}

// ---------------- bf16 MFMA GEMM: C = A[M][K] @ Bt[N][K]^T ----------------
// Tile 128 x BN, BK=32, double-buffered LDS via global_load_lds, split-K = gridDim.z.
// EPI 0: store raw f32 partial (offset z*M*N). EPI 1: +bias,BN,ReLU -> bf16.
// EPI 3: +bias,BN,ReLU,BN,ReLU -> bf16 (+DOT: accumulate out . wq[:,0:2] per block).
template<int EPI, int BN, bool DOT>
__global__ __launch_bounds__(256) void k_gemm(
    const unsigned short* __restrict__ A, const unsigned short* __restrict__ Bt,
    int M, int N, int K,
    const float* __restrict__ bias,
    const float* __restrict__ g1p, const float* __restrict__ b1p,
    const float* __restrict__ m1p, const float* __restrict__ v1p,
    const float* __restrict__ g2p, const float* __restrict__ b2p,
    const float* __restrict__ m2p, const float* __restrict__ v2p,
    float* __restrict__ outf, unsigned short* __restrict__ outb,
    const float* __restrict__ wq, float* __restrict__ part, int slotbase)
{
    __shared__ alignas(16) unsigned short As[2][128 * 32];
    __shared__ alignas(16) unsigned short Bs[2][BN * 32];
    const int t = threadIdx.x;
    const int lane = t & 63, w = t >> 6;
    const int wr = w >> 1, wc = w & 1;
    const int l15 = lane & 15, l4 = lane >> 4;
    const int m0 = blockIdx.x * 128, n0 = blockIdx.y * BN;
    constexpr int NJ = BN / 32;          // 16-col frags per wave in N
    constexpr int WCW = BN / 2;          // wave column width

    f32x4 acc[4][NJ];
#pragma unroll
    for (int i = 0; i < 4; ++i)
#pragma unroll
        for (int j = 0; j < NJ; ++j) acc[i][j] = (f32x4){0.f, 0.f, 0.f, 0.f};

    const int Kc = K / gridDim.z;
    const int kbase = blockIdx.z * Kc;
    const unsigned short* Ab = A + (size_t)m0 * K + kbase;
    const unsigned short* Bb = Bt + (size_t)n0 * K + kbase;
    const unsigned short* ga0 = Ab + (size_t)(t >> 2) * K + (t & 3) * 8;
    const unsigned short* ga1 = ga0 + (size_t)64 * K;
    const unsigned short* gb0 = Bb + (size_t)(t >> 2) * K + (t & 3) * 8;
    const unsigned short* gb1 = gb0 + (size_t)64 * K;

    auto stage = [&](int kt, int buf) {
        const int ko = kt * 32;
        GLOAD(ga0 + ko, &As[buf][t * 8]);
        GLOAD(ga1 + ko, &As[buf][(t + 256) * 8]);
        GLOAD(gb0 + ko, &Bs[buf][t * 8]);
        if constexpr (BN == 128) {
            GLOAD(gb1 + ko, &Bs[buf][(t + 256) * 8]);
        }
    };

    const int nk = Kc >> 5;
    stage(0, 0);
    __syncthreads();                     // drains vmcnt: buf0 ready
    for (int kt = 0; kt < nk; ++kt) {
        const int cur = kt & 1;
        if (kt + 1 < nk) stage(kt + 1, cur ^ 1);
        short8 aF[4], bF[NJ];
#pragma unroll
        for (int i = 0; i < 4; ++i)
            aF[i] = *(const short8*)(&As[cur][(wr * 64 + i * 16 + l15) * 32 + 8 * l4]);
#pragma unroll
        for (int j = 0; j < NJ; ++j)
            bF[j] = *(const short8*)(&Bs[cur][(wc * WCW + j * 16 + l15) * 32 + 8 * l4]);
#pragma unroll
        for (int i = 0; i < 4; ++i)
#pragma unroll
            for (int j = 0; j < NJ; ++j)
                acc[i][j] = __builtin_amdgcn_mfma_f32_16x16x32_bf16(aF[i], bF[j], acc[i][j], 0, 0, 0);
        __syncthreads();                 // next buffer ready, all reads done
    }

    const int mrow = m0 + wr * 64;
    float* op = outf + (EPI == 0 ? (size_t)blockIdx.z * M * N : 0);
    float d0 = 0.f, d1 = 0.f;
#pragma unroll
    for (int j = 0; j < NJ; ++j) {
        const int cg = n0 + wc * WCW + j * 16 + l15;
        float bi = 0.f, sc1 = 1.f, sh1 = 0.f, sc2 = 1.f, sh2 = 0.f;
        if (EPI >= 1) {
            bi = bias[cg];
            sc1 = rsqrtf(v1p[cg] + 1e-5f) * g1p[cg];
            sh1 = b1p[cg] - m1p[cg] * sc1;
        }
        if (EPI == 3) {
            sc2 = rsqrtf(v2p[cg] + 1e-5f) * g2p[cg];
            sh2 = b2p[cg] - m2p[cg] * sc2;
        }
#pragma unroll
        for (int i = 0; i < 4; ++i) {
#pragma unroll
            for (int r = 0; r < 4; ++r) {
                const int rg = mrow + i * 16 + l4 * 4 + r;
                float x = acc[i][j][r];
                if (EPI == 0) {
                    op[(size_t)rg * N + cg] = x;
                } else if (EPI == 1) {
                    x = fmaxf((x + bi) * sc1 + sh1, 0.f);
                    outb[(size_t)rg * N + cg] = f2bf(x);
                } else {
                    x = fmaxf((x + bi) * sc1 + sh1, 0.f);
                    x = fmaxf(x * sc2 + sh2, 0.f);
                    outb[(size_t)rg * N + cg] = f2bf(x);
                    if constexpr (DOT) {
                        float2 wv = ((const float2*)wq)[(size_t)rg * N + cg];
                        d0 += x * wv.x; d1 += x * wv.y;
                    }
                }
            }
        }
    }
    if constexpr (DOT) {
        __shared__ float r0[256], r1[256];
        r0[t] = d0; r1[t] = d1;
        __syncthreads();
        for (int s = 128; s > 0; s >>= 1) {
            if (t < s) { r0[t] += r0[t + s]; r1[t] += r1[t + s]; }
            __syncthreads();
        }
        if (t == 0) {
            const int slot = slotbase + blockIdx.y * gridDim.x + blockIdx.x;
            part[2 * slot] = r0[0]; part[2 * slot + 1] = r1[0];
        }
    }
}

// sum 4 split-K partials -> G0
__global__ __launch_bounds__(256) void k_red4(const float* __restrict__ p, float* __restrict__ G0) {
    const long S = (long)NN * HH / 4;
    long i = blockIdx.x * 256L + threadIdx.x;
    float4 a = ((const float4*)p)[i];
    float4 b = ((const float4*)p)[i + S];
    float4 c = ((const float4*)p)[i + 2 * S];
    float4 d = ((const float4*)p)[i + 3 * S];
    float4 o;
    o.x = (a.x + b.x) + (c.x + d.x);
    o.y = (a.y + b.y) + (c.y + d.y);
    o.z = (a.z + b.z) + (c.z + d.z);
    o.w = (a.w + b.w) + (c.w + d.w);
    ((float4*)G0)[i] = o;
}

// ---------------- edge aggregation (gather-sum over sorted in-edges, 4x prefetch) ----------------
__global__ __launch_bounds__(128) void k_agg0(
    const float* __restrict__ G0, const int* __restrict__ starts, const int* __restrict__ sorted,
    const float* __restrict__ epsp, const float* __restrict__ bias,
    const float* __restrict__ bg, const float* __restrict__ bb,
    const float* __restrict__ bm, const float* __restrict__ bv,
    unsigned short* __restrict__ outb)
{
    const int d = blockIdx.x, t = threadIdx.x;
    const float ep = 1.0f + epsp[0];
    float4 own = ((const float4*)(G0 + (size_t)d * HH))[t];
    float sx = 0.f, sy = 0.f, sz = 0.f, sw = 0.f;
    const int e0 = starts[d], e1 = starts[d + 1];
    int i = e0;
    for (; i + 4 <= e1; i += 4) {
        int q0 = sorted[i], q1 = sorted[i + 1], q2 = sorted[i + 2], q3 = sorted[i + 3];
        float4 x0 = ((const float4*)(G0 + (size_t)q0 * HH))[t];
        float4 x1 = ((const float4*)(G0 + (size_t)q1 * HH))[t];
        float4 x2 = ((const float4*)(G0 + (size_t)q2 * HH))[t];
        float4 x3 = ((const float4*)(G0 + (size_t)q3 * HH))[t];
        sx += (x0.x + x1.x) + (x2.x + x3.x);
        sy += (x0.y + x1.y) + (x2.y + x3.y);
        sz += (x0.z + x1.z) + (x2.z + x3.z);
        sw += (x0.w + x1.w) + (x2.w + x3.w);
    }
    for (; i < e1; ++i) {
        float4 x = ((const float4*)(G0 + (size_t)sorted[i] * HH))[t];
        sx += x.x; sy += x.y; sz += x.z; sw += x.w;
    }
    float4 bi = ((const float4*)bias)[t];
    float4 g4 = ((const float4*)bg)[t];
    float4 b4 = ((const float4*)bb)[t];
    float4 m4 = ((const float4*)bm)[t];
    float4 v4 = ((const float4*)bv)[t];
    float x0 = ep * own.x + sx + bi.x;
    float x1 = ep * own.y + sy + bi.y;
    float x2 = ep * own.z + sz + bi.z;
    float x3 = ep * own.w + sw + bi.w;
    x0 = fmaxf((x0 - m4.x) * rsqrtf(v4.x + 1e-5f) * g4.x + b4.x, 0.f);
    x1 = fmaxf((x1 - m4.y) * rsqrtf(v4.y + 1e-5f) * g4.y + b4.y, 0.f);
    x2 = fmaxf((x2 - m4.z) * rsqrtf(v4.z + 1e-5f) * g4.z + b4.z, 0.f);
    x3 = fmaxf((x3 - m4.w) * rsqrtf(v4.w + 1e-5f) * g4.w + b4.w, 0.f);
    ushort4 o; o.x = f2bf(x0); o.y = f2bf(x1); o.z = f2bf(x2); o.w = f2bf(x3);
    ((ushort4*)(outb + (size_t)d * HH))[t] = o;
}

// hidden layers: h is bf16 now
__global__ __launch_bounds__(128) void k_aggL(
    const unsigned short* __restrict__ hsrc, const int* __restrict__ starts,
    const int* __restrict__ sorted, const float* __restrict__ epsp,
    unsigned short* __restrict__ outb)
{
    const int d = blockIdx.x, t = threadIdx.x;
    const float ep = 1.0f + epsp[0];
    ushort4 ow = ((const ushort4*)(hsrc + (size_t)d * HH))[t];
    float sx = 0.f, sy = 0.f, sz = 0.f, sw = 0.f;
    const int e0 = starts[d], e1 = starts[d + 1];
    int i = e0;
    for (; i + 4 <= e1; i += 4) {
        int q0 = sorted[i], q1 = sorted[i + 1], q2 = sorted[i + 2], q3 = sorted[i + 3];
        ushort4 x0 = ((const ushort4*)(hsrc + (size_t)q0 * HH))[t];
        ushort4 x1 = ((const ushort4*)(hsrc + (size_t)q1 * HH))[t];
        ushort4 x2 = ((const ushort4*)(hsrc + (size_t)q2 * HH))[t];
        ushort4 x3 = ((const ushort4*)(hsrc + (size_t)q3 * HH))[t];
        sx += (b2f(x0.x) + b2f(x1.x)) + (b2f(x2.x) + b2f(x3.x));
        sy += (b2f(x0.y) + b2f(x1.y)) + (b2f(x2.y) + b2f(x3.y));
        sz += (b2f(x0.z) + b2f(x1.z)) + (b2f(x2.z) + b2f(x3.z));
        sw += (b2f(x0.w) + b2f(x1.w)) + (b2f(x2.w) + b2f(x3.w));
    }
    for (; i < e1; ++i) {
        ushort4 x = ((const ushort4*)(hsrc + (size_t)sorted[i] * HH))[t];
        sx += b2f(x.x); sy += b2f(x.y); sz += b2f(x.z); sw += b2f(x.w);
    }
    ushort4 o;
    o.x = f2bf(ep * b2f(ow.x) + sx);
    o.y = f2bf(ep * b2f(ow.y) + sy);
    o.z = f2bf(ep * b2f(ow.z) + sz);
    o.w = f2bf(ep * b2f(ow.w) + sw);
    ((ushort4*)(outb + (size_t)d * HH))[t] = o;
}

__global__ __launch_bounds__(256) void k_final(const float* __restrict__ part, int nslot,
                                               const float* __restrict__ bp0, const float* __restrict__ bpR,
                                               float* __restrict__ out) {
    __shared__ float s0[256], s1[256];
    int t = threadIdx.x;
    float a0 = 0.f, a1 = 0.f;
    for (int i = t; i < nslot; i += 256) { a0 += part[2 * i]; a1 += part[2 * i + 1]; }
    s0[t] = a0; s1[t] = a1;
    __syncthreads();
    for (int s = 128; s > 0; s >>= 1) {
        if (t < s) { s0[t] += s0[t + s]; s1[t] += s1[t + s]; }
        __syncthreads();
    }
    if (t == 0) {
        out[0] = s0[0] + bp0[0] + bpR[0] + bpR[2] + bpR[4] + bpR[6];
        out[1] = s1[0] + bp0[1] + bpR[1] + bpR[3] + bpR[5] + bpR[7];
    }
}

extern "C" void kernel_launch(void* const* d_in, const int* in_sizes, int n_in,
                              void* d_out, int out_size, void* d_ws, size_t ws_size,
                              hipStream_t stream)
{
    const float* feat = (const float*)d_in[0];
    const int*   esrc = (const int*)d_in[1];
    const int*   edst = (const int*)d_in[2];
    const float* eps0 = (const float*)d_in[3];
    const float* W0a  = (const float*)d_in[4];
    const float* b0a  = (const float*)d_in[5];
    const float* W0b  = (const float*)d_in[6];
    const float* b0b  = (const float*)d_in[7];
    const float* bn0a_g = (const float*)d_in[8];
    const float* bn0a_b = (const float*)d_in[9];
    const float* bn0a_m = (const float*)d_in[10];
    const float* bn0a_v = (const float*)d_in[11];
    const float* bnA0_g = (const float*)d_in[12];
    const float* bnA0_b = (const float*)d_in[13];
    const float* bnA0_m = (const float*)d_in[14];
    const float* bnA0_v = (const float*)d_in[15];
    const float* bnO0_g = (const float*)d_in[16];
    const float* bnO0_b = (const float*)d_in[17];
    const float* bnO0_m = (const float*)d_in[18];
    const float* bnO0_v = (const float*)d_in[19];
    const float* epsR = (const float*)d_in[20];
    const float* WRa  = (const float*)d_in[21];
    const float* bRa  = (const float*)d_in[22];
    const float* WRb  = (const float*)d_in[23];
    const float* bRb  = (const float*)d_in[24];
    const float* bnRa_g = (const float*)d_in[25];
    const float* bnRa_b = (const float*)d_in[26];
    const float* bnRa_m = (const float*)d_in[27];
    const float* bnRa_v = (const float*)d_in[28];
    const float* bnAR_g = (const float*)d_in[29];
    const float* bnAR_b = (const float*)d_in[30];
    const float* bnAR_m = (const float*)d_in[31];
    const float* bnAR_v = (const float*)d_in[32];
    const float* bnOR_g = (const float*)d_in[33];
    const float* bnOR_b = (const float*)d_in[34];
    const float* bnOR_m = (const float*)d_in[35];
    const float* bnOR_v = (const float*)d_in[36];
    const float* Wp0 = (const float*)d_in[37];
    const float* bp0 = (const float*)d_in[38];
    const float* WpR = (const float*)d_in[39];
    const float* bpR = (const float*)d_in[40];
    float* out = (float*)d_out;

    char* ws = (char*)d_ws;
    const size_t MB = 1024 * 1024;
    int*   cnt    = (int*)(ws + 0x00000);
    int*   starts = (int*)(ws + 0x10000);
    int*   cursor = (int*)(ws + 0x20000);
    int*   sorted = (int*)(ws + 0x30000);     // 256 KiB
    float* part   = (float*)(ws + 0x70000);   // 5120*2 f32 (40 KiB)
    unsigned short* featb = (unsigned short*)(ws + 1 * MB);    // [4096][4096] bf16, 32 MiB
    unsigned short* w0at  = (unsigned short*)(ws + 33 * MB);   // [512][4096] bf16, 4 MiB
    unsigned short* wt    = (unsigned short*)(ws + 37 * MB);   // 7 x [512][512] bf16
    float* G0 = (float*)(ws + 41 * MB);                        // [4096][512] f32
    unsigned short* xb = (unsigned short*)(ws + 49 * MB);      // [4096][512] bf16
    unsigned short* yb = (unsigned short*)(ws + 53 * MB);      // [4096][512] bf16
    unsigned short* hb = (unsigned short*)(ws + 57 * MB);      // 4 x [4096][512] bf16 (16 MiB)
    float* pbuf = (float*)(ws + 57 * MB);                      // split-K partials, 32 MiB
                                                               // (dead before first hb write)

    // ---- edge sort ----
    hipMemsetAsync(ws, 0, 0x30000, stream);
    k_hist<<<EE / 256, 256, 0, stream>>>(edst, cnt);
    k_scan<<<1, 256, 0, stream>>>(cnt, starts);
    k_scatter<<<EE / 256, 256, 0, stream>>>(esrc, edst, starts, cursor, sorted);
    k_binsort<<<NN / 256, 256, 0, stream>>>(starts, sorted);

    // ---- precision prep (+ fused feat.Wp0 readout dot) ----
    k_cvtdot0<<<4096, 256, 0, stream>>>(feat, Wp0, featb, part);
    k_transcvt<<<dim3(NN / 32, HH / 32), 256, 0, stream>>>(W0a, w0at, NN, HH);
    k_transcvt7<<<dim3(HH / 32, HH / 32, 7), 256, 0, stream>>>(W0b, WRa, WRb, wt);

    // ---- layer 0 (reassociated: G0 = feat@W0a first, then aggregate) ----
    k_gemm<0, 128, false><<<dim3(32, 4, 4), 256, 0, stream>>>(featb, w0at, NN, HH, NN,
        nullptr, nullptr, nullptr, nullptr, nullptr, nullptr, nullptr, nullptr, nullptr,
        pbuf, nullptr, nullptr, nullptr, 0);
    k_red4<<<2048, 256, 0, stream>>>(pbuf, G0);
    k_agg0<<<NN, 128, 0, stream>>>(G0, starts, sorted, eps0, b0a,
                                   bn0a_g, bn0a_b, bn0a_m, bn0a_v, xb);
    k_gemm<3, 64, true><<<dim3(32, 8), 256, 0, stream>>>(xb, wt, NN, HH, HH,
        b0b, bnA0_g, bnA0_b, bnA0_m, bnA0_v, bnO0_g, bnO0_b, bnO0_m, bnO0_v,
        nullptr, hb, WpR, part, 4096);

    // ---- layers 1..3 ----
    for (int i = 0; i < 3; ++i) {
        const unsigned short* hp = hb + (size_t)i * NN * HH;
        unsigned short* hn = hb + (size_t)(i + 1) * NN * HH;
        k_aggL<<<NN, 128, 0, stream>>>(hp, starts, sorted, epsR + i, xb);
        k_gemm<1, 64, false><<<dim3(32, 8), 256, 0, stream>>>(xb, wt + (size_t)(1 + i) * HH * HH, NN, HH, HH,
            bRa + (size_t)i * HH,
            bnRa_g + (size_t)i * HH, bnRa_b + (size_t)i * HH, bnRa_m + (size_t)i * HH, bnRa_v + (size_t)i * HH,
            nullptr, nullptr, nullptr, nullptr,
            nullptr, yb, nullptr, nullptr, 0);
        k_gemm<3, 64, true><<<dim3(32, 8), 256, 0, stream>>>(yb, wt + (size_t)(4 + i) * HH * HH, NN, HH, HH,
            bRb + (size_t)i * HH,
            bnAR_g + (size_t)i * HH, bnAR_b + (size_t)i * HH, bnAR_m + (size_t)i * HH, bnAR_v + (size_t)i * HH,
            bnOR_g + (size_t)i * HH, bnOR_b + (size_t)i * HH, bnOR_m + (size_t)i * HH, bnOR_v + (size_t)i * HH,
            nullptr, hn, WpR + (size_t)(i + 1) * NN * HH * 2, part, 4096 + (i + 1) * 256);
    }

    // ---- jumping-knowledge readout final reduce ----
    k_final<<<1, 256, 0, stream>>>(part, 4096 + 4 * 256, bp0, bpR, out);
}

// Round 5
// 299.579 us; speedup vs baseline: 1.1673x; 1.0521x over previous
//
#include <hip/hip_runtime.h>
#include <cstdint>
#include <cstddef>

typedef __attribute__((ext_vector_type(8))) short short8;   // 8 bf16 (4 VGPRs)
typedef __attribute__((ext_vector_type(4))) float f32x4;    // 4 fp32 acc
typedef __attribute__((ext_vector_type(4))) float f4;
typedef __attribute__((ext_vector_type(2))) float f2;
typedef __attribute__((ext_vector_type(4))) unsigned short us4;

#define NN 4096
#define HH 512
#define EE 65536

// async global->LDS, 16B per lane (dest must be linear: base + lane*16)
#define GLOAD(gp, lp) __builtin_amdgcn_global_load_lds( \
    (const __attribute__((address_space(1))) void*)(gp), \
    (__attribute__((address_space(3))) void*)(lp), 16, 0, 0)

__device__ __forceinline__ unsigned short f2bf(float x) {
    union { float f; unsigned u; } un; un.f = x;
    unsigned r = un.u + 0x7fffu + ((un.u >> 16) & 1u);   // round-to-nearest-even
    return (unsigned short)(r >> 16);
}
__device__ __forceinline__ float b2f(unsigned short v) {
    union { unsigned u; float f; } un; un.u = ((unsigned)v) << 16; return un.f;
}

// ---------------- edge sort: fused hist+scan (1 block), scatter, binsort ----------------
__global__ __launch_bounds__(1024) void k_histscan(const int* __restrict__ edst,
                                                   int* __restrict__ starts) {
    __shared__ int cnt[NN];
    __shared__ int wtot[16], woff[16];
    const int t = threadIdx.x;
    for (int i = t; i < NN; i += 1024) cnt[i] = 0;
    __syncthreads();
    for (int i = t; i < EE; i += 1024) atomicAdd(&cnt[edst[i]], 1);
    __syncthreads();
    const int b = t * 4;
    const int c0 = cnt[b], c1 = cnt[b + 1], c2 = cnt[b + 2], c3 = cnt[b + 3];
    const int s = c0 + c1 + c2 + c3;
    const int lane = t & 63, wv = t >> 6;
    int inc = s;
    for (int d = 1; d < 64; d <<= 1) {
        int v = __shfl_up(inc, d);
        if (lane >= d) inc += v;
    }
    if (lane == 63) wtot[wv] = inc;
    __syncthreads();
    if (t == 0) {
        int a = 0;
        for (int i = 0; i < 16; ++i) { woff[i] = a; a += wtot[i]; }
        starts[NN] = a;
    }
    __syncthreads();
    int run = woff[wv] + inc - s;
    starts[b] = run; run += c0;
    starts[b + 1] = run; run += c1;
    starts[b + 2] = run; run += c2;
    starts[b + 3] = run;
}

__global__ void k_scatter(const int* __restrict__ src, const int* __restrict__ dst,
                          const int* __restrict__ starts, int* __restrict__ cursor,
                          int* __restrict__ sorted) {
    int e = blockIdx.x * 256 + threadIdx.x;
    if (e < EE) {
        int d = dst[e];
        int p = starts[d] + atomicAdd(&cursor[d], 1);
        sorted[p] = src[e];
    }
}

__global__ void k_binsort(const int* __restrict__ starts, int* __restrict__ a) {
    int d = blockIdx.x * 256 + threadIdx.x;
    if (d < NN) {
        int s = starts[d], e = starts[d + 1];
        for (int i = s + 1; i < e; ++i) {
            int v = a[i]; int j = i - 1;
            while (j >= s && a[j] > v) { a[j + 1] = a[j]; --j; }
            a[j + 1] = v;
        }
    }
}

// ---------------- fused: feat f32 -> bf16 convert + feat . Wp0 partial dot ----------------
// Block owns 1024 consecutive float4s of feat (16 KiB) and 2048 float4s of Wp0.
// ALL global accesses are unit-stride across lanes; feat stashed in LDS, dot pairs
// fetched via ds_read_b64 at q*8 (conflict-free 2 lanes/bank).
__global__ __launch_bounds__(256) void k_cvtdot0(const float* __restrict__ feat,
                                                 const float* __restrict__ w,
                                                 unsigned short* __restrict__ featb,
                                                 float* __restrict__ part) {
    __shared__ f4 fs[1024];
    __shared__ float s0[256], s1[256];
    const int t = threadIdx.x;
    const long B0 = (long)blockIdx.x * 1024;
    const f4* ff = (const f4*)feat;
    const f4* ww = (const f4*)w;
    // phase 1: feat load (unit-stride), stash LDS, convert+store bf16
    f4 v[4];
#pragma unroll
    for (int k = 0; k < 4; ++k)
        v[k] = __builtin_nontemporal_load(ff + B0 + k * 256 + t);
#pragma unroll
    for (int k = 0; k < 4; ++k) {
        fs[k * 256 + t] = v[k];
        us4 o;
        o.x = f2bf(v[k].x); o.y = f2bf(v[k].y); o.z = f2bf(v[k].z); o.w = f2bf(v[k].w);
        ((us4*)featb)[B0 + k * 256 + t] = o;
    }
    // phase 2: w load (unit-stride), pair with LDS feat halves
    f4 wv[8];
#pragma unroll
    for (int k = 0; k < 8; ++k)
        wv[k] = __builtin_nontemporal_load(ww + 2 * B0 + k * 256 + t);
    __syncthreads();
    float a0 = 0.f, a1 = 0.f;
#pragma unroll
    for (int k = 0; k < 8; ++k) {
        const int q = k * 256 + t;
        f2 fp = *(const f2*)((const char*)fs + (size_t)q * 8);
        a0 += fp.x * wv[k].x + fp.y * wv[k].z;
        a1 += fp.x * wv[k].y + fp.y * wv[k].w;
    }
    s0[t] = a0; s1[t] = a1;
    __syncthreads();
    for (int s = 128; s > 0; s >>= 1) {
        if (t < s) { s0[t] += s0[t + s]; s1[t] += s1[t + s]; }
        __syncthreads();
    }
    if (t == 0) { part[2 * blockIdx.x] = s0[0]; part[2 * blockIdx.x + 1] = s1[0]; }
}

// ---------------- batched weight transpose/convert ----------------
// z<7: 512x512 (z=0 W0b, z=1..3 WRa, z=4..6 WRb) -> wt[z]; z=7: W0a 4096x512 -> w0at
__global__ __launch_bounds__(256) void k_transcvt8(const float* __restrict__ W0a,
                                                   const float* __restrict__ W0b,
                                                   const float* __restrict__ WRa,
                                                   const float* __restrict__ WRb,
                                                   unsigned short* __restrict__ w0at,
                                                   unsigned short* __restrict__ wt) {
    __shared__ float tile[32][33];
    const int z = blockIdx.z;
    const float* W;
    unsigned short* Wt;
    int K;
    if (z == 7) {
        W = W0a; Wt = w0at; K = NN;
    } else {
        if (blockIdx.x >= 16 || blockIdx.y >= 16) return;
        W = (z == 0) ? W0b : (z < 4) ? WRa + (size_t)(z - 1) * HH * HH
                                     : WRb + (size_t)(z - 4) * HH * HH;
        Wt = wt + (size_t)z * HH * HH; K = HH;
    }
    const int k0 = blockIdx.x * 32, n0 = blockIdx.y * 32;
    const int tx = threadIdx.x & 31, ty = threadIdx.x >> 5;
    for (int r = ty; r < 32; r += 8)
        tile[r][tx] = W[(size_t)(k0 + r) * HH + n0 + tx];
    __syncthreads();
    for (int r = ty; r < 32; r += 8)
        Wt[(size_t)(n0 + r) * K + k0 + tx] = f2bf(tile[tx][r]);
}

// ---------------- gemm0: C = A[M][K] @ Bt[N][K]^T, 128x128 tile, split-K, f32 out ----------------
__global__ __launch_bounds__(256) void k_gemm0(
    const unsigned short* __restrict__ A, const unsigned short* __restrict__ Bt,
    int M, int N, int K, float* __restrict__ outf)
{
    __shared__ alignas(16) unsigned short As[2][128 * 32];
    __shared__ alignas(16) unsigned short Bs[2][128 * 32];
    const int t = threadIdx.x;
    const int lane = t & 63, w = t >> 6;
    const int wr = w >> 1, wc = w & 1;
    const int l15 = lane & 15, l4 = lane >> 4;
    const int m0 = blockIdx.x * 128, n0 = blockIdx.y * 128;

    f32x4 acc[4][4];
#pragma unroll
    for (int i = 0; i < 4; ++i)
#pragma unroll
        for (int j = 0; j < 4; ++j) acc[i][j] = (f32x4){0.f, 0.f, 0.f, 0.f};

    const int Kc = K / gridDim.z;
    const int kbase = blockIdx.z * Kc;
    const unsigned short* ga0 = A + (size_t)m0 * K + kbase + (size_t)(t >> 2) * K + (t & 3) * 8;
    const unsigned short* ga1 = ga0 + (size_t)64 * K;
    const unsigned short* gb0 = Bt + (size_t)n0 * K + kbase + (size_t)(t >> 2) * K + (t & 3) * 8;
    const unsigned short* gb1 = gb0 + (size_t)64 * K;

    auto stage = [&](int kt, int buf) {
        const int ko = kt * 32;
        GLOAD(ga0 + ko, &As[buf][t * 8]);
        GLOAD(ga1 + ko, &As[buf][(t + 256) * 8]);
        GLOAD(gb0 + ko, &Bs[buf][t * 8]);
        GLOAD(gb1 + ko, &Bs[buf][(t + 256) * 8]);
    };

    const int nk = Kc >> 5;
    stage(0, 0);
    __syncthreads();
    for (int kt = 0; kt < nk; ++kt) {
        const int cur = kt & 1;
        if (kt + 1 < nk) stage(kt + 1, cur ^ 1);
        short8 aF[4], bF[4];
#pragma unroll
        for (int i = 0; i < 4; ++i)
            aF[i] = *(const short8*)(&As[cur][(wr * 64 + i * 16 + l15) * 32 + 8 * l4]);
#pragma unroll
        for (int j = 0; j < 4; ++j)
            bF[j] = *(const short8*)(&Bs[cur][(wc * 64 + j * 16 + l15) * 32 + 8 * l4]);
#pragma unroll
        for (int i = 0; i < 4; ++i)
#pragma unroll
            for (int j = 0; j < 4; ++j)
                acc[i][j] = __builtin_amdgcn_mfma_f32_16x16x32_bf16(aF[i], bF[j], acc[i][j], 0, 0, 0);
        __syncthreads();
    }

    const int mrow = m0 + wr * 64;
    float* op = outf + (size_t)blockIdx.z * M * N;
#pragma unroll
    for (int j = 0; j < 4; ++j) {
        const int cg = n0 + wc * 64 + j * 16 + l15;
#pragma unroll
        for (int i = 0; i < 4; ++i)
#pragma unroll
            for (int r = 0; r < 4; ++r)
                op[(size_t)(mrow + i * 16 + l4 * 4 + r) * N + cg] = acc[i][j][r];
    }
}

// ---------------- H x H GEMM: 8 waves (512 thr), tile 128x64, BK=32 ----------------
// EPI 1: +bias,BN,ReLU -> bf16. EPI 3: +bias,BN,ReLU,BN,ReLU -> bf16 (+DOT).
template<int EPI, bool DOT>
__global__ __launch_bounds__(512) void k_gemmH(
    const unsigned short* __restrict__ A, const unsigned short* __restrict__ Bt,
    const float* __restrict__ bias,
    const float* __restrict__ g1p, const float* __restrict__ b1p,
    const float* __restrict__ m1p, const float* __restrict__ v1p,
    const float* __restrict__ g2p, const float* __restrict__ b2p,
    const float* __restrict__ m2p, const float* __restrict__ v2p,
    unsigned short* __restrict__ outb,
    const float* __restrict__ wq, float* __restrict__ part, int slotbase)
{
    constexpr int K = HH, N = HH;
    __shared__ alignas(16) unsigned short As[2][128 * 32];
    __shared__ alignas(16) unsigned short Bs[2][64 * 32];
    const int t = threadIdx.x;
    const int lane = t & 63, w = t >> 6;
    const int wr = w >> 1, wc = w & 1;            // 4 row-waves x 2 col-waves
    const int l15 = lane & 15, l4 = lane >> 4;
    const int m0 = blockIdx.x * 128, n0 = blockIdx.y * 64;

    f32x4 acc[2][2];
#pragma unroll
    for (int i = 0; i < 2; ++i)
#pragma unroll
        for (int j = 0; j < 2; ++j) acc[i][j] = (f32x4){0.f, 0.f, 0.f, 0.f};

    // A: 512 chunks of 16B, one per thread. B: 256 chunks, threads 0..255 (waves 0-3).
    const unsigned short* ga = A + (size_t)m0 * K + (size_t)(t >> 2) * K + (t & 3) * 8;
    const unsigned short* gb = Bt + (size_t)n0 * K + (size_t)(t >> 2) * K + (t & 3) * 8;

    auto stage = [&](int kt, int buf) {
        const int ko = kt * 32;
        GLOAD(ga + ko, &As[buf][t * 8]);
        if (t < 256) GLOAD(gb + ko, &Bs[buf][t * 8]);
    };

    const int nk = K >> 5;                        // 16
    stage(0, 0);
    __syncthreads();
    for (int kt = 0; kt < nk; ++kt) {
        const int cur = kt & 1;
        if (kt + 1 < nk) stage(kt + 1, cur ^ 1);
        short8 aF[2], bF[2];
#pragma unroll
        for (int i = 0; i < 2; ++i)
            aF[i] = *(const short8*)(&As[cur][(wr * 32 + i * 16 + l15) * 32 + 8 * l4]);
#pragma unroll
        for (int j = 0; j < 2; ++j)
            bF[j] = *(const short8*)(&Bs[cur][(wc * 32 + j * 16 + l15) * 32 + 8 * l4]);
#pragma unroll
        for (int i = 0; i < 2; ++i)
#pragma unroll
            for (int j = 0; j < 2; ++j)
                acc[i][j] = __builtin_amdgcn_mfma_f32_16x16x32_bf16(aF[i], bF[j], acc[i][j], 0, 0, 0);
        __syncthreads();
    }

    const int mrow = m0 + wr * 32;
    float d0 = 0.f, d1 = 0.f;
#pragma unroll
    for (int j = 0; j < 2; ++j) {
        const int cg = n0 + wc * 32 + j * 16 + l15;
        const float bi = bias[cg];
        const float sc1 = rsqrtf(v1p[cg] + 1e-5f) * g1p[cg];
        const float sh1 = b1p[cg] - m1p[cg] * sc1;
        float sc2 = 1.f, sh2 = 0.f;
        if (EPI == 3) {
            sc2 = rsqrtf(v2p[cg] + 1e-5f) * g2p[cg];
            sh2 = b2p[cg] - m2p[cg] * sc2;
        }
#pragma unroll
        for (int i = 0; i < 2; ++i) {
#pragma unroll
            for (int r = 0; r < 4; ++r) {
                const int rg = mrow + i * 16 + l4 * 4 + r;
                float x = acc[i][j][r];
                x = fmaxf((x + bi) * sc1 + sh1, 0.f);
                if (EPI == 3) x = fmaxf(x * sc2 + sh2, 0.f);
                outb[(size_t)rg * N + cg] = f2bf(x);
                if constexpr (DOT) {
                    float2 wvv = ((const float2*)wq)[(size_t)rg * N + cg];
                    d0 += x * wvv.x; d1 += x * wvv.y;
                }
            }
        }
    }
    if constexpr (DOT) {
        __shared__ float r0[512], r1[512];
        r0[t] = d0; r1[t] = d1;
        __syncthreads();
        for (int s = 256; s > 0; s >>= 1) {
            if (t < s) { r0[t] += r0[t + s]; r1[t] += r1[t + s]; }
            __syncthreads();
        }
        if (t == 0) {
            const int slot = slotbase + blockIdx.y * gridDim.x + blockIdx.x;
            part[2 * slot] = r0[0]; part[2 * slot + 1] = r1[0];
        }
    }
}

// sum 4 split-K partials -> bf16 G0b
__global__ __launch_bounds__(256) void k_red4b(const float* __restrict__ p,
                                               unsigned short* __restrict__ G0b) {
    const long S = (long)NN * HH / 4;
    long i = blockIdx.x * 256L + threadIdx.x;
    float4 a = ((const float4*)p)[i];
    float4 b = ((const float4*)p)[i + S];
    float4 c = ((const float4*)p)[i + 2 * S];
    float4 d = ((const float4*)p)[i + 3 * S];
    us4 o;
    o.x = f2bf((a.x + b.x) + (c.x + d.x));
    o.y = f2bf((a.y + b.y) + (c.y + d.y));
    o.z = f2bf((a.z + b.z) + (c.z + d.z));
    o.w = f2bf((a.w + b.w) + (c.w + d.w));
    ((us4*)G0b)[i] = o;
}

// ---------------- edge aggregation ----------------
// layer 0 (G0 bf16): xb = bf16(ReLU(BN((1+eps)*G0[d] + sum G0[src] + bias)))
__global__ __launch_bounds__(128) void k_agg0(
    const unsigned short* __restrict__ G0, const int* __restrict__ starts,
    const int* __restrict__ sorted, const float* __restrict__ epsp,
    const float* __restrict__ bias,
    const float* __restrict__ bg, const float* __restrict__ bb,
    const float* __restrict__ bm, const float* __restrict__ bv,
    unsigned short* __restrict__ outb)
{
    const int d = blockIdx.x, t = threadIdx.x;
    const float ep = 1.0f + epsp[0];
    ushort4 ow = ((const ushort4*)(G0 + (size_t)d * HH))[t];
    float sx = 0.f, sy = 0.f, sz = 0.f, sw = 0.f;
    const int e0 = starts[d], e1 = starts[d + 1];
    int i = e0;
    for (; i + 4 <= e1; i += 4) {
        int q0 = sorted[i], q1 = sorted[i + 1], q2 = sorted[i + 2], q3 = sorted[i + 3];
        ushort4 x0 = ((const ushort4*)(G0 + (size_t)q0 * HH))[t];
        ushort4 x1 = ((const ushort4*)(G0 + (size_t)q1 * HH))[t];
        ushort4 x2 = ((const ushort4*)(G0 + (size_t)q2 * HH))[t];
        ushort4 x3 = ((const ushort4*)(G0 + (size_t)q3 * HH))[t];
        sx += (b2f(x0.x) + b2f(x1.x)) + (b2f(x2.x) + b2f(x3.x));
        sy += (b2f(x0.y) + b2f(x1.y)) + (b2f(x2.y) + b2f(x3.y));
        sz += (b2f(x0.z) + b2f(x1.z)) + (b2f(x2.z) + b2f(x3.z));
        sw += (b2f(x0.w) + b2f(x1.w)) + (b2f(x2.w) + b2f(x3.w));
    }
    for (; i < e1; ++i) {
        ushort4 x = ((const ushort4*)(G0 + (size_t)sorted[i] * HH))[t];
        sx += b2f(x.x); sy += b2f(x.y); sz += b2f(x.z); sw += b2f(x.w);
    }
    float4 bi = ((const float4*)bias)[t];
    float4 g4 = ((const float4*)bg)[t];
    float4 b4 = ((const float4*)bb)[t];
    float4 m4 = ((const float4*)bm)[t];
    float4 v4 = ((const float4*)bv)[t];
    float x0 = ep * b2f(ow.x) + sx + bi.x;
    float x1 = ep * b2f(ow.y) + sy + bi.y;
    float x2 = ep * b2f(ow.z) + sz + bi.z;
    float x3 = ep * b2f(ow.w) + sw + bi.w;
    x0 = fmaxf((x0 - m4.x) * rsqrtf(v4.x + 1e-5f) * g4.x + b4.x, 0.f);
    x1 = fmaxf((x1 - m4.y) * rsqrtf(v4.y + 1e-5f) * g4.y + b4.y, 0.f);
    x2 = fmaxf((x2 - m4.z) * rsqrtf(v4.z + 1e-5f) * g4.z + b4.z, 0.f);
    x3 = fmaxf((x3 - m4.w) * rsqrtf(v4.w + 1e-5f) * g4.w + b4.w, 0.f);
    ushort4 o; o.x = f2bf(x0); o.y = f2bf(x1); o.z = f2bf(x2); o.w = f2bf(x3);
    ((ushort4*)(outb + (size_t)d * HH))[t] = o;
}

// hidden layers (h bf16)
__global__ __launch_bounds__(128) void k_aggL(
    const unsigned short* __restrict__ hsrc, const int* __restrict__ starts,
    const int* __restrict__ sorted, const float* __restrict__ epsp,
    unsigned short* __restrict__ outb)
{
    const int d = blockIdx.x, t = threadIdx.x;
    const float ep = 1.0f + epsp[0];
    ushort4 ow = ((const ushort4*)(hsrc + (size_t)d * HH))[t];
    float sx = 0.f, sy = 0.f, sz = 0.f, sw = 0.f;
    const int e0 = starts[d], e1 = starts[d + 1];
    int i = e0;
    for (; i + 4 <= e1; i += 4) {
        int q0 = sorted[i], q1 = sorted[i + 1], q2 = sorted[i + 2], q3 = sorted[i + 3];
        ushort4 x0 = ((const ushort4*)(hsrc + (size_t)q0 * HH))[t];
        ushort4 x1 = ((const ushort4*)(hsrc + (size_t)q1 * HH))[t];
        ushort4 x2 = ((const ushort4*)(hsrc + (size_t)q2 * HH))[t];
        ushort4 x3 = ((const ushort4*)(hsrc + (size_t)q3 * HH))[t];
        sx += (b2f(x0.x) + b2f(x1.x)) + (b2f(x2.x) + b2f(x3.x));
        sy += (b2f(x0.y) + b2f(x1.y)) + (b2f(x2.y) + b2f(x3.y));
        sz += (b2f(x0.z) + b2f(x1.z)) + (b2f(x2.z) + b2f(x3.z));
        sw += (b2f(x0.w) + b2f(x1.w)) + (b2f(x2.w) + b2f(x3.w));
    }
    for (; i < e1; ++i) {
        ushort4 x = ((const ushort4*)(hsrc + (size_t)sorted[i] * HH))[t];
        sx += b2f(x.x); sy += b2f(x.y); sz += b2f(x.z); sw += b2f(x.w);
    }
    ushort4 o;
    o.x = f2bf(ep * b2f(ow.x) + sx);
    o.y = f2bf(ep * b2f(ow.y) + sy);
    o.z = f2bf(ep * b2f(ow.z) + sz);
    o.w = f2bf(ep * b2f(ow.w) + sw);
    ((ushort4*)(outb + (size_t)d * HH))[t] = o;
}

__global__ __launch_bounds__(256) void k_final(const float* __restrict__ part, int nslot,
                                               const float* __restrict__ bp0, const float* __restrict__ bpR,
                                               float* __restrict__ out) {
    __shared__ float s0[256], s1[256];
    int t = threadIdx.x;
    float a0 = 0.f, a1 = 0.f;
    for (int i = t; i < nslot; i += 256) { a0 += part[2 * i]; a1 += part[2 * i + 1]; }
    s0[t] = a0; s1[t] = a1;
    __syncthreads();
    for (int s = 128; s > 0; s >>= 1) {
        if (t < s) { s0[t] += s0[t + s]; s1[t] += s1[t + s]; }
        __syncthreads();
    }
    if (t == 0) {
        out[0] = s0[0] + bp0[0] + bpR[0] + bpR[2] + bpR[4] + bpR[6];
        out[1] = s1[0] + bp0[1] + bpR[1] + bpR[3] + bpR[5] + bpR[7];
    }
}

extern "C" void kernel_launch(void* const* d_in, const int* in_sizes, int n_in,
                              void* d_out, int out_size, void* d_ws, size_t ws_size,
                              hipStream_t stream)
{
    const float* feat = (const float*)d_in[0];
    const int*   esrc = (const int*)d_in[1];
    const int*   edst = (const int*)d_in[2];
    const float* eps0 = (const float*)d_in[3];
    const float* W0a  = (const float*)d_in[4];
    const float* b0a  = (const float*)d_in[5];
    const float* W0b  = (const float*)d_in[6];
    const float* b0b  = (const float*)d_in[7];
    const float* bn0a_g = (const float*)d_in[8];
    const float* bn0a_b = (const float*)d_in[9];
    const float* bn0a_m = (const float*)d_in[10];
    const float* bn0a_v = (const float*)d_in[11];
    const float* bnA0_g = (const float*)d_in[12];
    const float* bnA0_b = (const float*)d_in[13];
    const float* bnA0_m = (const float*)d_in[14];
    const float* bnA0_v = (const float*)d_in[15];
    const float* bnO0_g = (const float*)d_in[16];
    const float* bnO0_b = (const float*)d_in[17];
    const float* bnO0_m = (const float*)d_in[18];
    const float* bnO0_v = (const float*)d_in[19];
    const float* epsR = (const float*)d_in[20];
    const float* WRa  = (const float*)d_in[21];
    const float* bRa  = (const float*)d_in[22];
    const float* WRb  = (const float*)d_in[23];
    const float* bRb  = (const float*)d_in[24];
    const float* bnRa_g = (const float*)d_in[25];
    const float* bnRa_b = (const float*)d_in[26];
    const float* bnRa_m = (const float*)d_in[27];
    const float* bnRa_v = (const float*)d_in[28];
    const float* bnAR_g = (const float*)d_in[29];
    const float* bnAR_b = (const float*)d_in[30];
    const float* bnAR_m = (const float*)d_in[31];
    const float* bnAR_v = (const float*)d_in[32];
    const float* bnOR_g = (const float*)d_in[33];
    const float* bnOR_b = (const float*)d_in[34];
    const float* bnOR_m = (const float*)d_in[35];
    const float* bnOR_v = (const float*)d_in[36];
    const float* Wp0 = (const float*)d_in[37];
    const float* bp0 = (const float*)d_in[38];
    const float* WpR = (const float*)d_in[39];
    const float* bpR = (const float*)d_in[40];
    float* out = (float*)d_out;

    char* ws = (char*)d_ws;
    const size_t MB = 1024 * 1024;
    int*   starts = (int*)(ws + 0x10000);
    int*   cursor = (int*)(ws + 0x20000);
    int*   sorted = (int*)(ws + 0x30000);     // 256 KiB
    float* part   = (float*)(ws + 0x70000);   // 5120*2 f32 (40 KiB)
    unsigned short* featb = (unsigned short*)(ws + 1 * MB);    // [4096][4096] bf16, 32 MiB
    unsigned short* w0at  = (unsigned short*)(ws + 33 * MB);   // [512][4096] bf16, 4 MiB
    unsigned short* wt    = (unsigned short*)(ws + 37 * MB);   // 7 x [512][512] bf16
    unsigned short* G0b   = (unsigned short*)(ws + 41 * MB);   // [4096][512] bf16, 4 MiB
    unsigned short* xb = (unsigned short*)(ws + 49 * MB);      // [4096][512] bf16
    unsigned short* yb = (unsigned short*)(ws + 53 * MB);      // [4096][512] bf16
    unsigned short* hb = (unsigned short*)(ws + 57 * MB);      // 4 x [4096][512] bf16 (16 MiB)
    float* pbuf = (float*)(ws + 57 * MB);                      // split-K partials, 32 MiB
                                                               // (dead before first hb write)

    // ---- edge sort ----
    hipMemsetAsync(cursor, 0, NN * sizeof(int), stream);
    k_histscan<<<1, 1024, 0, stream>>>(edst, starts);
    k_scatter<<<EE / 256, 256, 0, stream>>>(esrc, edst, starts, cursor, sorted);
    k_binsort<<<NN / 256, 256, 0, stream>>>(starts, sorted);

    // ---- precision prep (+ fused feat.Wp0 readout dot) ----
    k_cvtdot0<<<4096, 256, 0, stream>>>(feat, Wp0, featb, part);
    k_transcvt8<<<dim3(NN / 32, HH / 32, 8), 256, 0, stream>>>(W0a, W0b, WRa, WRb, w0at, wt);

    // ---- layer 0 (reassociated: G0 = feat@W0a first, then aggregate) ----
    k_gemm0<<<dim3(32, 4, 4), 256, 0, stream>>>(featb, w0at, NN, HH, NN, pbuf);
    k_red4b<<<2048, 256, 0, stream>>>(pbuf, G0b);
    k_agg0<<<NN, 128, 0, stream>>>(G0b, starts, sorted, eps0, b0a,
                                   bn0a_g, bn0a_b, bn0a_m, bn0a_v, xb);
    k_gemmH<3, true><<<dim3(32, 8), 512, 0, stream>>>(xb, wt,
        b0b, bnA0_g, bnA0_b, bnA0_m, bnA0_v, bnO0_g, bnO0_b, bnO0_m, bnO0_v,
        hb, WpR, part, 4096);

    // ---- layers 1..3 ----
    for (int i = 0; i < 3; ++i) {
        const unsigned short* hp = hb + (size_t)i * NN * HH;
        unsigned short* hn = hb + (size_t)(i + 1) * NN * HH;
        k_aggL<<<NN, 128, 0, stream>>>(hp, starts, sorted, epsR + i, xb);
        k_gemmH<1, false><<<dim3(32, 8), 512, 0, stream>>>(xb, wt + (size_t)(1 + i) * HH * HH,
            bRa + (size_t)i * HH,
            bnRa_g + (size_t)i * HH, bnRa_b + (size_t)i * HH, bnRa_m + (size_t)i * HH, bnRa_v + (size_t)i * HH,
            nullptr, nullptr, nullptr, nullptr,
            yb, nullptr, nullptr, 0);
        k_gemmH<3, true><<<dim3(32, 8), 512, 0, stream>>>(yb, wt + (size_t)(4 + i) * HH * HH,
            bRb + (size_t)i * HH,
            bnAR_g + (size_t)i * HH, bnAR_b + (size_t)i * HH, bnAR_m + (size_t)i * HH, bnAR_v + (size_t)i * HH,
            bnOR_g + (size_t)i * HH, bnOR_b + (size_t)i * HH, bnOR_m + (size_t)i * HH, bnOR_v + (size_t)i * HH,
            hn, WpR + (size_t)(i + 1) * NN * HH * 2, part, 4096 + (i + 1) * 256);
    }

    // ---- jumping-knowledge readout final reduce ----
    k_final<<<1, 256, 0, stream>>>(part, 4096 + 4 * 256, bp0, bpR, out);
}